// Round 1
// baseline (417.812 us; speedup 1.0000x reference)
//
#include <hip/hip_runtime.h>
#include <math.h>

#define FDIM 96
#define CAP 64

static __device__ __forceinline__ float wave_sum(float v) {
    for (int off = 32; off; off >>= 1) v += __shfl_xor(v, off, 64);
    return v;
}

// ---- K1: x_tan = logmap0(x) ----
__global__ __launch_bounds__(256) void k_logmap(const float* __restrict__ x,
                                                float* __restrict__ xt, int n) {
    int wid = (blockIdx.x * blockDim.x + threadIdx.x) >> 6;
    int lane = threadIdx.x & 63;
    if (wid >= n) return;
    const float* xr = x + (size_t)wid * FDIM;
    float a0 = xr[lane];
    float a1 = (lane < 32) ? xr[64 + lane] : 0.f;
    float ss = wave_sum(a0 * a0 + a1 * a1);
    float norm = fmaxf(sqrtf(ss), 1e-15f);
    float arg = fminf(fmaxf(norm, -1.f + 1e-15f), 1.f - 1e-15f);
    float s = atanhf(arg) / norm;
    float* ot = xt + (size_t)wid * FDIM;
    ot[lane] = a0 * s;
    if (lane < 32) ot[64 + lane] = a1 * s;
}

// ---- K2: degrees (by row) + padded-CSR fill (by col) ----
__global__ __launch_bounds__(256) void k_count(const int* __restrict__ row,
                                               const int* __restrict__ col,
                                               int* __restrict__ deg,
                                               int* __restrict__ cnt,
                                               int* __restrict__ srcp, int E) {
    int e = blockIdx.x * blockDim.x + threadIdx.x;
    if (e >= E) return;
    int r = row[e], c = col[e];
    atomicAdd(&deg[r], 1);
    int pos = atomicAdd(&cnt[c], 1);
    if (pos < CAP) srcp[(size_t)c * CAP + pos] = r;
}

// ---- K3: dinv = deg^-0.5 (0 where deg==0) ----
__global__ __launch_bounds__(256) void k_dinv(const int* __restrict__ deg,
                                              float* __restrict__ dinv, int n) {
    int i = blockIdx.x * blockDim.x + threadIdx.x;
    if (i >= n) return;
    int d = deg[i];
    dinv[i] = (d > 0) ? (float)(1.0 / sqrt((double)d)) : 0.f;
}

// ---- K4: updated = leaky_relu(x_tan @ W_up^T, 0.01) ----
__global__ __launch_bounds__(256) void k_gemm(const float* __restrict__ xt,
                                              const float* __restrict__ W,
                                              float* __restrict__ up, int n) {
    __shared__ float Ws[FDIM][FDIM + 1];   // padded: conflict-free
    __shared__ float xs[8][FDIM];
    int t = threadIdx.x;
    for (int idx = t; idx < FDIM * FDIM; idx += 256)
        Ws[idx / FDIM][idx % FDIM] = W[idx];
    int row0 = blockIdx.x * 8;
    for (int idx = t; idx < 8 * FDIM; idx += 256) {
        int r = idx / FDIM, k = idx % FDIM;
        int gr = row0 + r;
        xs[r][k] = (gr < n) ? xt[(size_t)gr * FDIM + k] : 0.f;
    }
    __syncthreads();
    int r = t >> 5, c0 = t & 31;
    int gr = row0 + r;
    if (gr >= n) return;
    float a0 = 0.f, a1 = 0.f, a2 = 0.f;
#pragma unroll 8
    for (int k = 0; k < FDIM; ++k) {
        float xv = xs[r][k];
        a0 = fmaf(xv, Ws[c0][k], a0);
        a1 = fmaf(xv, Ws[c0 + 32][k], a1);
        a2 = fmaf(xv, Ws[c0 + 64][k], a2);
    }
    float* o = up + (size_t)gr * FDIM;
    o[c0]      = a0 > 0.f ? a0 : 0.01f * a0;
    o[c0 + 32] = a1 > 0.f ? a1 : 0.01f * a1;
    o[c0 + 64] = a2 > 0.f ? a2 : 0.01f * a2;
}

// ---- K5: info -> score -> sel ----
__global__ __launch_bounds__(256) void k_pass1(const float* __restrict__ xt,
                                               const int* __restrict__ srcp,
                                               const int* __restrict__ cnt,
                                               const float* __restrict__ dinv,
                                               float* __restrict__ sel, int n) {
    int wid = (blockIdx.x * blockDim.x + threadIdx.x) >> 6;
    int lane = threadIdx.x & 63;
    if (wid >= n) return;
    float di = dinv[wid];
    int m = cnt[wid]; if (m > CAP) m = CAP;
    const int* sp = srcp + (size_t)wid * CAP;
    const float* xi = xt + (size_t)wid * FDIM;
    float a0 = xi[lane];
    float a1 = (lane < 32) ? xi[64 + lane] : 0.f;
    for (int k = 0; k < m; ++k) {
        int j = sp[k];
        float coef = -di * dinv[j];
        const float* xj = xt + (size_t)j * FDIM;
        a0 = fmaf(coef, xj[lane], a0);
        if (lane < 32) a1 = fmaf(coef, xj[64 + lane], a1);
    }
    float sc = wave_sum(fabsf(a0) + fabsf(a1));
    if (lane == 0) sel[wid] = (sc > 1.0f) ? 1.f : 0.f;
}

// ---- K6: sum_neigh / sum_sel -> wp = sel * sigmoid(concat @ W_lw^T) ----
__global__ __launch_bounds__(256) void k_pass2(const float* __restrict__ up,
                                               const int* __restrict__ srcp,
                                               const int* __restrict__ cnt,
                                               const float* __restrict__ sel,
                                               const float* __restrict__ Wlw,
                                               float* __restrict__ wp, int n) {
    int wid = (blockIdx.x * blockDim.x + threadIdx.x) >> 6;
    int lane = threadIdx.x & 63;
    if (wid >= n) return;
    int m = cnt[wid]; if (m > CAP) m = CAP;
    const int* sp = srcp + (size_t)wid * CAP;
    float sn0 = 0.f, sn1 = 0.f, ss0 = 0.f, ss1 = 0.f;
    for (int k = 0; k < m; ++k) {
        int j = sp[k];
        float sj = sel[j];                 // wave-uniform
        const float* uj = up + (size_t)j * FDIM;
        float u0 = uj[lane];
        float u1 = (lane < 32) ? uj[64 + lane] : 0.f;
        sn0 += u0; sn1 += u1;
        if (sj > 0.f) { ss0 += u0; ss1 += u1; }
    }
    float t = ss0 * Wlw[lane] + sn0 * Wlw[96 + lane];
    if (lane < 32) t += ss1 * Wlw[64 + lane] + sn1 * Wlw[160 + lane];
    t = wave_sum(t);
    if (lane == 0) {
        float w = 1.f / (1.f + expf(-t));
        wp[wid] = (sel[wid] > 0.f) ? w : 0.f;
    }
}

// ---- K7: A_x -> out = proj(expmap0(updated + relu(A_x))) ----
__global__ __launch_bounds__(256) void k_pass3(const float* __restrict__ up,
                                               const int* __restrict__ srcp,
                                               const int* __restrict__ cnt,
                                               const float* __restrict__ wp,
                                               float* __restrict__ out, int n) {
    int wid = (blockIdx.x * blockDim.x + threadIdx.x) >> 6;
    int lane = threadIdx.x & 63;
    if (wid >= n) return;
    int m = cnt[wid]; if (m > CAP) m = CAP;
    const int* sp = srcp + (size_t)wid * CAP;
    float a0 = 0.f, a1 = 0.f;
    for (int k = 0; k < m; ++k) {
        int j = sp[k];
        float pj = wp[j];                  // wave-uniform
        if (pj != 0.f) {
            const float* uj = up + (size_t)j * FDIM;
            a0 = fmaf(pj, uj[lane], a0);
            if (lane < 32) a1 = fmaf(pj, uj[64 + lane], a1);
        }
    }
    a0 = fmaxf(a0, 0.f);
    a1 = fmaxf(a1, 0.f);
    const float* ui = up + (size_t)wid * FDIM;
    float o0 = ui[lane] + a0;
    float o1 = (lane < 32) ? ui[64 + lane] + a1 : 0.f;
    float ss = wave_sum(o0 * o0 + o1 * o1);
    float norm = fmaxf(sqrtf(ss), 1e-15f);
    float th = tanhf(norm);
    float s = th / norm;
    const float maxn = 1.0f - 4e-3f;
    if (th > maxn) s = maxn / norm;        // proj: ||expmap0|| = tanh(norm)
    float* o = out + (size_t)wid * FDIM;
    o[lane] = s * o0;
    if (lane < 32) o[64 + lane] = s * o1;
}

extern "C" void kernel_launch(void* const* d_in, const int* in_sizes, int n_in,
                              void* d_out, int out_size, void* d_ws, size_t ws_size,
                              hipStream_t stream) {
    const float* x   = (const float*)d_in[0];
    const int*  eidx = (const int*)d_in[1];
    const float* Wup = (const float*)d_in[2];
    const float* Wlw = (const float*)d_in[3];
    float* out = (float*)d_out;

    int N = in_sizes[0] / FDIM;
    int E = in_sizes[1] / 2;
    const int* row = eidx;
    const int* col = eidx + E;

    char* ws = (char*)d_ws;
    size_t off = 0;
    auto alloc = [&](size_t bytes) {
        void* p = ws + off;
        off += (bytes + 255) & ~(size_t)255;
        return p;
    };
    float* x_tan = (float*)alloc((size_t)N * FDIM * 4);
    float* up    = (float*)alloc((size_t)N * FDIM * 4);
    int*   deg   = (int*)alloc((size_t)N * 4);
    int*   cnt   = (int*)alloc((size_t)N * 4);
    float* dinv  = (float*)alloc((size_t)N * 4);
    float* sel   = (float*)alloc((size_t)N * 4);
    float* wp    = (float*)alloc((size_t)N * 4);
    int*   srcp  = (int*)alloc((size_t)N * CAP * 4);

    hipMemsetAsync(deg, 0, (size_t)N * 4, stream);
    hipMemsetAsync(cnt, 0, (size_t)N * 4, stream);

    dim3 blk(256);
    dim3 gridN4((N + 3) / 4);          // wave-per-node kernels
    dim3 gridE((E + 255) / 256);
    dim3 gridN((N + 255) / 256);
    dim3 gridG((N + 7) / 8);

    k_logmap<<<gridN4, blk, 0, stream>>>(x, x_tan, N);
    k_count <<<gridE,  blk, 0, stream>>>(row, col, deg, cnt, srcp, E);
    k_dinv  <<<gridN,  blk, 0, stream>>>(deg, dinv, N);
    k_gemm  <<<gridG,  blk, 0, stream>>>(x_tan, Wup, up, N);
    k_pass1 <<<gridN4, blk, 0, stream>>>(x_tan, srcp, cnt, dinv, sel, N);
    k_pass2 <<<gridN4, blk, 0, stream>>>(up, srcp, cnt, sel, Wlw, wp, N);
    k_pass3 <<<gridN4, blk, 0, stream>>>(up, srcp, cnt, wp, out, N);
}

// Round 2
// 254.360 us; speedup vs baseline: 1.6426x; 1.6426x over previous
//
#include <hip/hip_runtime.h>
#include <math.h>

#define FDIM 96
#define CAP 64

static __device__ __forceinline__ float wave_sum(float v) {
    for (int off = 32; off; off >>= 1) v += __shfl_xor(v, off, 64);
    return v;
}
static __device__ __forceinline__ float bf_lo(unsigned u) { return __uint_as_float(u << 16); }
static __device__ __forceinline__ float bf_hi(unsigned u) { return __uint_as_float(u & 0xffff0000u); }
static __device__ __forceinline__ unsigned bf_rne(float f) {
    unsigned x = __float_as_uint(f);
    return (x + 0x7fffu + ((x >> 16) & 1u)) >> 16;
}

// ---- K1: x_tan = logmap0(x) ----
__global__ __launch_bounds__(256) void k_logmap(const float* __restrict__ x,
                                                float* __restrict__ xt, int n) {
    int wid = (blockIdx.x * blockDim.x + threadIdx.x) >> 6;
    int lane = threadIdx.x & 63;
    if (wid >= n) return;
    const float2* xr = (const float2*)(x + (size_t)wid * FDIM);
    float2 v = (lane < 48) ? xr[lane] : make_float2(0.f, 0.f);
    float ss = wave_sum(v.x * v.x + v.y * v.y);
    float norm = fmaxf(sqrtf(ss), 1e-15f);
    float arg = fminf(fmaxf(norm, -1.f + 1e-15f), 1.f - 1e-15f);
    float s = atanhf(arg) / norm;
    float2* ot = (float2*)(xt + (size_t)wid * FDIM);
    if (lane < 48) ot[lane] = make_float2(v.x * s, v.y * s);
}

// ---- K2: degrees (by row) + padded-CSR fill (by col) ----
__global__ __launch_bounds__(256) void k_count(const int* __restrict__ row,
                                               const int* __restrict__ col,
                                               int* __restrict__ deg,
                                               int* __restrict__ cnt,
                                               int* __restrict__ srcp, int E) {
    int e = blockIdx.x * blockDim.x + threadIdx.x;
    if (e >= E) return;
    int r = row[e], c = col[e];
    atomicAdd(&deg[r], 1);
    int pos = atomicAdd(&cnt[c], 1);
    if (pos < CAP) srcp[(size_t)c * CAP + pos] = r;
}

// ---- K3: dinv = deg^-0.5 (0 where deg==0) ----
__global__ __launch_bounds__(256) void k_dinv(const int* __restrict__ deg,
                                              float* __restrict__ dinv, int n) {
    int i = blockIdx.x * blockDim.x + threadIdx.x;
    if (i >= n) return;
    int d = deg[i];
    dinv[i] = (d > 0) ? (float)(1.0 / sqrt((double)d)) : 0.f;
}

// ---- K4: updated = leaky_relu(x_tan @ W_up^T); also pack bf16 copy ----
__global__ __launch_bounds__(256) void k_gemm(const float* __restrict__ xt,
                                              const float* __restrict__ W,
                                              float* __restrict__ up,
                                              unsigned* __restrict__ upb, int n) {
    __shared__ float Ws[FDIM][FDIM + 1];   // padded: conflict-free
    __shared__ float xs[8][FDIM];
    int t = threadIdx.x;
    for (int idx = t; idx < FDIM * FDIM; idx += 256)
        Ws[idx / FDIM][idx % FDIM] = W[idx];
    int row0 = blockIdx.x * 8;
    for (int idx = t; idx < 8 * FDIM; idx += 256) {
        int r = idx / FDIM, k = idx % FDIM;
        int gr = row0 + r;
        xs[r][k] = (gr < n) ? xt[(size_t)gr * FDIM + k] : 0.f;
    }
    __syncthreads();
    int r = t >> 5, c0 = t & 31;
    int gr = row0 + r;
    float a0 = 0.f, a1 = 0.f, a2 = 0.f;
#pragma unroll 8
    for (int k = 0; k < FDIM; ++k) {
        float xv = xs[r][k];
        a0 = fmaf(xv, Ws[c0][k], a0);
        a1 = fmaf(xv, Ws[c0 + 32][k], a1);
        a2 = fmaf(xv, Ws[c0 + 64][k], a2);
    }
    a0 = a0 > 0.f ? a0 : 0.01f * a0;
    a1 = a1 > 0.f ? a1 : 0.01f * a1;
    a2 = a2 > 0.f ? a2 : 0.01f * a2;
    if (gr < n) {
        float* o = up + (size_t)gr * FDIM;
        o[c0] = a0; o[c0 + 32] = a1; o[c0 + 64] = a2;
    }
    __syncthreads();               // done reading xs as input
    xs[r][c0] = a0; xs[r][c0 + 32] = a1; xs[r][c0 + 64] = a2;
    __syncthreads();
    for (int idx = t; idx < 8 * 48; idx += 256) {
        int r2 = idx / 48, c = idx % 48;
        int g = row0 + r2;
        if (g < n)
            upb[(size_t)g * 48 + c] = bf_rne(xs[r2][2 * c]) | (bf_rne(xs[r2][2 * c + 1]) << 16);
    }
}

// ---- K5: info -> score -> sel  (fp32, 4x-unrolled float2 gather) ----
__global__ __launch_bounds__(256) void k_pass1(const float* __restrict__ xt,
                                               const int* __restrict__ srcp,
                                               const int* __restrict__ cnt,
                                               const float* __restrict__ dinv,
                                               float* __restrict__ sel, int n) {
    int wid = (blockIdx.x * blockDim.x + threadIdx.x) >> 6;
    int lane = threadIdx.x & 63;
    if (wid >= n) return;
    float di = dinv[wid];
    int m = cnt[wid]; if (m > CAP) m = CAP;
    const int* sp = srcp + (size_t)wid * CAP;
    int jl = 0; float dvl = 0.f;
    if (lane < m) { jl = sp[lane]; dvl = dinv[jl]; }
    const float2* xi = (const float2*)(xt + (size_t)wid * FDIM);
    float2 own = (lane < 48) ? xi[lane] : make_float2(0.f, 0.f);
    float ax = own.x, ay = own.y;
    float bx = 0.f, by = 0.f, cx = 0.f, cy = 0.f, dx = 0.f, dy = 0.f;
    for (int k = 0; k < m; k += 4) {
        int rem = m - k;
        int j0 = __shfl(jl, k, 64);                 float c0 = -di * __shfl(dvl, k, 64);
        int j1 = rem > 1 ? __shfl(jl, k + 1, 64) : j0; float c1 = rem > 1 ? -di * __shfl(dvl, k + 1, 64) : 0.f;
        int j2 = rem > 2 ? __shfl(jl, k + 2, 64) : j0; float c2 = rem > 2 ? -di * __shfl(dvl, k + 2, 64) : 0.f;
        int j3 = rem > 3 ? __shfl(jl, k + 3, 64) : j0; float c3 = rem > 3 ? -di * __shfl(dvl, k + 3, 64) : 0.f;
        if (lane < 48) {
            float2 v0 = ((const float2*)(xt + (size_t)j0 * FDIM))[lane];
            float2 v1 = ((const float2*)(xt + (size_t)j1 * FDIM))[lane];
            float2 v2 = ((const float2*)(xt + (size_t)j2 * FDIM))[lane];
            float2 v3 = ((const float2*)(xt + (size_t)j3 * FDIM))[lane];
            ax = fmaf(c0, v0.x, ax); ay = fmaf(c0, v0.y, ay);
            bx = fmaf(c1, v1.x, bx); by = fmaf(c1, v1.y, by);
            cx = fmaf(c2, v2.x, cx); cy = fmaf(c2, v2.y, cy);
            dx = fmaf(c3, v3.x, dx); dy = fmaf(c3, v3.y, dy);
        }
    }
    float ix = (ax + bx) + (cx + dx);
    float iy = (ay + by) + (cy + dy);
    float sc = wave_sum(fabsf(ix) + fabsf(iy));
    if (lane == 0) sel[wid] = (sc > 1.0f) ? 1.f : 0.f;
}

// ---- K6: sum_neigh / sum_sel (bf16 gather) -> wp ----
__global__ __launch_bounds__(256) void k_pass2(const unsigned* __restrict__ upb,
                                               const int* __restrict__ srcp,
                                               const int* __restrict__ cnt,
                                               const float* __restrict__ sel,
                                               const float* __restrict__ Wlw,
                                               float* __restrict__ wp, int n) {
    int wid = (blockIdx.x * blockDim.x + threadIdx.x) >> 6;
    int lane = threadIdx.x & 63;
    if (wid >= n) return;
    int m = cnt[wid]; if (m > CAP) m = CAP;
    const int* sp = srcp + (size_t)wid * CAP;
    int jl = 0; float sl = 0.f;
    if (lane < m) { jl = sp[lane]; sl = sel[jl]; }
    float nax = 0.f, nay = 0.f, nbx = 0.f, nby = 0.f, ncx = 0.f, ncy = 0.f, ndx = 0.f, ndy = 0.f;
    float sax = 0.f, say = 0.f, sbx = 0.f, sby = 0.f, scx = 0.f, scy = 0.f, sdx = 0.f, sdy = 0.f;
    for (int k = 0; k < m; k += 4) {
        int rem = m - k;
        int j0 = __shfl(jl, k, 64);                 float s0 = __shfl(sl, k, 64);
        int j1 = rem > 1 ? __shfl(jl, k + 1, 64) : j0; float s1 = rem > 1 ? __shfl(sl, k + 1, 64) : 0.f;
        int j2 = rem > 2 ? __shfl(jl, k + 2, 64) : j0; float s2 = rem > 2 ? __shfl(sl, k + 2, 64) : 0.f;
        int j3 = rem > 3 ? __shfl(jl, k + 3, 64) : j0; float s3 = rem > 3 ? __shfl(sl, k + 3, 64) : 0.f;
        float g1 = rem > 1 ? 1.f : 0.f, g2 = rem > 2 ? 1.f : 0.f, g3 = rem > 3 ? 1.f : 0.f;
        if (lane < 48) {
            unsigned u0 = upb[(size_t)j0 * 48 + lane];
            unsigned u1 = upb[(size_t)j1 * 48 + lane];
            unsigned u2 = upb[(size_t)j2 * 48 + lane];
            unsigned u3 = upb[(size_t)j3 * 48 + lane];
            float v0x = bf_lo(u0), v0y = bf_hi(u0);
            float v1x = bf_lo(u1), v1y = bf_hi(u1);
            float v2x = bf_lo(u2), v2y = bf_hi(u2);
            float v3x = bf_lo(u3), v3y = bf_hi(u3);
            nax += v0x;              nay += v0y;
            nbx = fmaf(g1, v1x, nbx); nby = fmaf(g1, v1y, nby);
            ncx = fmaf(g2, v2x, ncx); ncy = fmaf(g2, v2y, ncy);
            ndx = fmaf(g3, v3x, ndx); ndy = fmaf(g3, v3y, ndy);
            sax = fmaf(s0, v0x, sax); say = fmaf(s0, v0y, say);
            sbx = fmaf(s1, v1x, sbx); sby = fmaf(s1, v1y, sby);
            scx = fmaf(s2, v2x, scx); scy = fmaf(s2, v2y, scy);
            sdx = fmaf(s3, v3x, sdx); sdy = fmaf(s3, v3y, sdy);
        }
    }
    float t = 0.f;
    if (lane < 48) {
        float snx = (nax + nbx) + (ncx + ndx), sny = (nay + nby) + (ncy + ndy);
        float ssx = (sax + sbx) + (scx + sdx), ssy = (say + sby) + (scy + sdy);
        const float2* Wl = (const float2*)Wlw;
        float2 ws = Wl[lane];        // weights for sum_sel, components 2l,2l+1
        float2 wn = Wl[48 + lane];   // weights for sum_neigh
        t = ssx * ws.x + ssy * ws.y + snx * wn.x + sny * wn.y;
    }
    t = wave_sum(t);
    if (lane == 0) {
        float w = 1.f / (1.f + expf(-t));
        wp[wid] = (sel[wid] > 0.f) ? w : 0.f;
    }
}

// ---- K7: A_x (ballot-sparse) -> out = proj(expmap0(updated + relu(A_x))) ----
__global__ __launch_bounds__(256) void k_pass3(const float* __restrict__ up,
                                               const unsigned* __restrict__ upb,
                                               const int* __restrict__ srcp,
                                               const int* __restrict__ cnt,
                                               const float* __restrict__ wp,
                                               float* __restrict__ out, int n) {
    int wid = (blockIdx.x * blockDim.x + threadIdx.x) >> 6;
    int lane = threadIdx.x & 63;
    if (wid >= n) return;
    int m = cnt[wid]; if (m > CAP) m = CAP;
    const int* sp = srcp + (size_t)wid * CAP;
    int jl = 0; float pl = 0.f;
    if (lane < m) { jl = sp[lane]; pl = wp[jl]; }
    unsigned long long ball = __ballot(pl != 0.f);
    float ax = 0.f, ay = 0.f;
    while (ball) {
        int b = __ffsll(ball) - 1;
        ball &= ball - 1;
        int j = __shfl(jl, b, 64);
        float p = __shfl(pl, b, 64);
        if (lane < 48) {
            unsigned u = upb[(size_t)j * 48 + lane];
            ax = fmaf(p, bf_lo(u), ax);
            ay = fmaf(p, bf_hi(u), ay);
        }
    }
    ax = fmaxf(ax, 0.f);
    ay = fmaxf(ay, 0.f);
    float2 own = (lane < 48) ? ((const float2*)(up + (size_t)wid * FDIM))[lane]
                             : make_float2(0.f, 0.f);
    float ox = own.x + ax, oy = own.y + ay;
    float ss = wave_sum(ox * ox + oy * oy);
    float norm = fmaxf(sqrtf(ss), 1e-15f);
    float th = tanhf(norm);
    float s = th / norm;
    const float maxn = 1.0f - 4e-3f;
    if (th > maxn) s = maxn / norm;
    if (lane < 48) {
        float2* o = (float2*)(out + (size_t)wid * FDIM);
        o[lane] = make_float2(s * ox, s * oy);
    }
}

extern "C" void kernel_launch(void* const* d_in, const int* in_sizes, int n_in,
                              void* d_out, int out_size, void* d_ws, size_t ws_size,
                              hipStream_t stream) {
    const float* x   = (const float*)d_in[0];
    const int*  eidx = (const int*)d_in[1];
    const float* Wup = (const float*)d_in[2];
    const float* Wlw = (const float*)d_in[3];
    float* out = (float*)d_out;

    int N = in_sizes[0] / FDIM;
    int E = in_sizes[1] / 2;
    const int* row = eidx;
    const int* col = eidx + E;

    char* ws = (char*)d_ws;
    size_t off = 0;
    auto alloc = [&](size_t bytes) {
        void* p = ws + off;
        off += (bytes + 255) & ~(size_t)255;
        return p;
    };
    float*    x_tan = (float*)alloc((size_t)N * FDIM * 4);
    float*    up    = (float*)alloc((size_t)N * FDIM * 4);
    unsigned* upb   = (unsigned*)alloc((size_t)N * 48 * 4);
    int*      deg   = (int*)alloc((size_t)N * 4);
    int*      cnt   = (int*)alloc((size_t)N * 4);
    float*    dinv  = (float*)alloc((size_t)N * 4);
    float*    sel   = (float*)alloc((size_t)N * 4);
    float*    wp    = (float*)alloc((size_t)N * 4);
    int*      srcp  = (int*)alloc((size_t)N * CAP * 4);

    hipMemsetAsync(deg, 0, (size_t)N * 4, stream);
    hipMemsetAsync(cnt, 0, (size_t)N * 4, stream);

    dim3 blk(256);
    dim3 gridN4((N + 3) / 4);          // wave-per-node kernels
    dim3 gridE((E + 255) / 256);
    dim3 gridN((N + 255) / 256);
    dim3 gridG((N + 7) / 8);

    k_logmap<<<gridN4, blk, 0, stream>>>(x, x_tan, N);
    k_count <<<gridE,  blk, 0, stream>>>(row, col, deg, cnt, srcp, E);
    k_dinv  <<<gridN,  blk, 0, stream>>>(deg, dinv, N);
    k_gemm  <<<gridG,  blk, 0, stream>>>(x_tan, Wup, up, upb, N);
    k_pass1 <<<gridN4, blk, 0, stream>>>(x_tan, srcp, cnt, dinv, sel, N);
    k_pass2 <<<gridN4, blk, 0, stream>>>(upb, srcp, cnt, sel, Wlw, wp, N);
    k_pass3 <<<gridN4, blk, 0, stream>>>(up, upb, srcp, cnt, wp, out, N);
}

// Round 3
// 229.008 us; speedup vs baseline: 1.8244x; 1.1107x over previous
//
#include <hip/hip_runtime.h>
#include <math.h>

#define FDIM 96
#define CAP 64

static __device__ __forceinline__ float wave_sum(float v) {
    for (int off = 32; off; off >>= 1) v += __shfl_xor(v, off, 64);
    return v;
}
static __device__ __forceinline__ float half_sum(float v) {   // within 32-aligned half-wave
    for (int off = 16; off; off >>= 1) v += __shfl_xor(v, off, 64);
    return v;
}
static __device__ __forceinline__ float bf_lo(unsigned u) { return __uint_as_float(u << 16); }
static __device__ __forceinline__ float bf_hi(unsigned u) { return __uint_as_float(u & 0xffff0000u); }
static __device__ __forceinline__ unsigned bf_rne(float f) {
    unsigned x = __float_as_uint(f);
    return (x + 0x7fffu + ((x >> 16) & 1u)) >> 16;
}

// ---- K_fused: [edge blocks: deg/cnt/srcp build] ++ [gemm blocks: logmap+gemm+bf16 packs]
__global__ __launch_bounds__(256) void k_fused(
    const float* __restrict__ x, const float* __restrict__ W,
    const int* __restrict__ row, const int* __restrict__ col,
    float* __restrict__ xt, unsigned* __restrict__ xtb,
    float* __restrict__ up, unsigned* __restrict__ upb,
    int* __restrict__ deg, int* __restrict__ cnt, int* __restrict__ srcp,
    int n, int E, int edgeBlocks)
{
    __shared__ float Ws[FDIM][49];     // one 48-wide k-chunk of W (21.4KB total LDS)
    __shared__ float xs[8][FDIM];
    int t = threadIdx.x;

    if ((int)blockIdx.x < edgeBlocks) {           // ---- edge path: 2 edges/thread
        int i2 = blockIdx.x * 256 + t;
        if (2 * i2 < E) {
            int2 rr = ((const int2*)row)[i2];
            int2 cc = ((const int2*)col)[i2];
            atomicAdd(&deg[rr.x], 1);
            atomicAdd(&deg[rr.y], 1);
            int p0 = atomicAdd(&cnt[cc.x], 1);
            if (p0 < CAP) srcp[(size_t)cc.x * CAP + p0] = rr.x;
            int p1 = atomicAdd(&cnt[cc.y], 1);
            if (p1 < CAP) srcp[(size_t)cc.y * CAP + p1] = rr.y;
        }
        return;
    }

    // ---- gemm path: 8 rows per block
    int row0 = (blockIdx.x - edgeBlocks) * 8;
    int r = t >> 5, c = t & 31;
    int gr = row0 + r;
    // logmap0
    float v0 = 0.f, v1 = 0.f, v2 = 0.f;
    if (gr < n) {
        const float* xr = x + (size_t)gr * FDIM;
        v0 = xr[c]; v1 = xr[c + 32]; v2 = xr[c + 64];
    }
    float ss = half_sum(v0 * v0 + v1 * v1 + v2 * v2);
    float norm = fmaxf(sqrtf(ss), 1e-15f);
    float s = atanhf(fminf(norm, 1.0f)) / norm;
    float u0 = v0 * s, u1 = v1 * s, u2 = v2 * s;
    xs[r][c] = u0; xs[r][c + 32] = u1; xs[r][c + 64] = u2;
    if (gr < n) {
        float* o = xt + (size_t)gr * FDIM;
        o[c] = u0; o[c + 32] = u1; o[c + 64] = u2;
    }
    __syncthreads();
    for (int idx = t; idx < 8 * 48; idx += 256) {      // pack bf16 x_tan
        int r2 = idx / 48, cc = idx % 48, g = row0 + r2;
        if (g < n)
            xtb[(size_t)g * 48 + cc] = bf_rne(xs[r2][2 * cc]) | (bf_rne(xs[r2][2 * cc + 1]) << 16);
    }
    // gemm: updated[c] = sum_k xt[k] * W[c][k], two 48-wide k-chunks
    float a0 = 0.f, a1 = 0.f, a2 = 0.f;
    for (int ch = 0; ch < 2; ++ch) {
        __syncthreads();
        for (int idx = t; idx < FDIM * 48; idx += 256) {
            int cw = idx / 48, kk = idx % 48;
            Ws[cw][kk] = W[(size_t)cw * FDIM + ch * 48 + kk];
        }
        __syncthreads();
        const float* xrow = &xs[r][ch * 48];
#pragma unroll 12
        for (int kk = 0; kk < 48; ++kk) {
            float xv = xrow[kk];
            a0 = fmaf(xv, Ws[c][kk], a0);
            a1 = fmaf(xv, Ws[c + 32][kk], a1);
            a2 = fmaf(xv, Ws[c + 64][kk], a2);
        }
    }
    a0 = a0 > 0.f ? a0 : 0.01f * a0;
    a1 = a1 > 0.f ? a1 : 0.01f * a1;
    a2 = a2 > 0.f ? a2 : 0.01f * a2;
    if (gr < n) {
        float* o = up + (size_t)gr * FDIM;
        o[c] = a0; o[c + 32] = a1; o[c + 64] = a2;
    }
    __syncthreads();
    xs[r][c] = a0; xs[r][c + 32] = a1; xs[r][c + 64] = a2;
    __syncthreads();
    for (int idx = t; idx < 8 * 48; idx += 256) {      // pack bf16 updated
        int r2 = idx / 48, cc = idx % 48, g = row0 + r2;
        if (g < n)
            upb[(size_t)g * 48 + cc] = bf_rne(xs[r2][2 * cc]) | (bf_rne(xs[r2][2 * cc + 1]) << 16);
    }
}

// ---- K_pass1: score via bf16 gather (8x unroll) + fp32 borderline recompute -> sel
__global__ __launch_bounds__(256) void k_pass1(
    const float* __restrict__ xt, const unsigned* __restrict__ xtb,
    const int* __restrict__ srcp, const int* __restrict__ cnt,
    const int* __restrict__ deg, float* __restrict__ sel, int n)
{
    int wid = (blockIdx.x * blockDim.x + threadIdx.x) >> 6;
    int lane = threadIdx.x & 63;
    if (wid >= n) return;
    int dsf = deg[wid];
    float di = dsf > 0 ? (float)(1.0 / sqrt((double)dsf)) : 0.f;
    int m = cnt[wid]; if (m > CAP) m = CAP;
    const int* sp = srcp + (size_t)wid * CAP;
    int jl = 0; float dvl = 0.f;
    if (lane < m) {
        jl = sp[lane];
        int dj = deg[jl];
        dvl = dj > 0 ? (float)(1.0 / sqrt((double)dj)) : 0.f;
    }
    const float2* xi = (const float2*)(xt + (size_t)wid * FDIM);
    float2 own = (lane < 48) ? xi[lane] : make_float2(0.f, 0.f);
    float accx[8], accy[8];
#pragma unroll
    for (int u = 0; u < 8; ++u) { accx[u] = 0.f; accy[u] = 0.f; }
    accx[0] = own.x; accy[0] = own.y;
    for (int k = 0; k < m; k += 8) {
        int j[8]; float cf[8];
#pragma unroll
        for (int u = 0; u < 8; ++u) {
            j[u]  = __shfl(jl, k + u, 64);
            cf[u] = -di * __shfl(dvl, k + u, 64);
        }
#pragma unroll
        for (int u = 0; u < 8; ++u) {
            if (k + u < m && lane < 48) {
                unsigned q = xtb[(size_t)j[u] * 48 + lane];
                accx[u] = fmaf(cf[u], bf_lo(q), accx[u]);
                accy[u] = fmaf(cf[u], bf_hi(q), accy[u]);
            }
        }
    }
    float ix = ((accx[0] + accx[1]) + (accx[2] + accx[3])) + ((accx[4] + accx[5]) + (accx[6] + accx[7]));
    float iy = ((accy[0] + accy[1]) + (accy[2] + accy[3])) + ((accy[4] + accy[5]) + (accy[6] + accy[7]));
    float sc = wave_sum(fabsf(ix) + fabsf(iy));
    if (sc > 0.99f && sc < 1.01f) {          // borderline: exact fp32 recompute
        float fx[4], fy[4];
#pragma unroll
        for (int u = 0; u < 4; ++u) { fx[u] = 0.f; fy[u] = 0.f; }
        fx[0] = own.x; fy[0] = own.y;
        for (int k = 0; k < m; k += 4) {
            int jj[4]; float cf[4];
#pragma unroll
            for (int u = 0; u < 4; ++u) {
                jj[u] = __shfl(jl, k + u, 64);
                cf[u] = -di * __shfl(dvl, k + u, 64);
            }
#pragma unroll
            for (int u = 0; u < 4; ++u) {
                if (k + u < m && lane < 48) {
                    float2 v = ((const float2*)(xt + (size_t)jj[u] * FDIM))[lane];
                    fx[u] = fmaf(cf[u], v.x, fx[u]);
                    fy[u] = fmaf(cf[u], v.y, fy[u]);
                }
            }
        }
        float rx = (fx[0] + fx[1]) + (fx[2] + fx[3]);
        float ry = (fy[0] + fy[1]) + (fy[2] + fy[3]);
        sc = wave_sum(fabsf(rx) + fabsf(ry));
    }
    if (lane == 0) sel[wid] = (sc > 1.0f) ? 1.f : 0.f;
}

// ---- K_pass2: only nodes with sel!=0 need wp (sigmoid of gathered sums)
__global__ __launch_bounds__(256) void k_pass2(
    const unsigned* __restrict__ upb, const int* __restrict__ srcp,
    const int* __restrict__ cnt, const float* __restrict__ sel,
    const float* __restrict__ Wlw, float* __restrict__ wp, int n)
{
    int wid = (blockIdx.x * blockDim.x + threadIdx.x) >> 6;
    int lane = threadIdx.x & 63;
    if (wid >= n) return;
    if (sel[wid] == 0.f) { if (lane == 0) wp[wid] = 0.f; return; }
    int m = cnt[wid]; if (m > CAP) m = CAP;
    const int* sp = srcp + (size_t)wid * CAP;
    int jl = 0; float sl = 0.f;
    if (lane < m) { jl = sp[lane]; sl = sel[jl]; }
    float snx = 0.f, sny = 0.f, ssx = 0.f, ssy = 0.f;
    for (int k = 0; k < m; ++k) {
        int j = __shfl(jl, k, 64);
        float sj = __shfl(sl, k, 64);
        if (lane < 48) {
            unsigned q = upb[(size_t)j * 48 + lane];
            float vx = bf_lo(q), vy = bf_hi(q);
            snx += vx; sny += vy;
            ssx = fmaf(sj, vx, ssx); ssy = fmaf(sj, vy, ssy);
        }
    }
    float tv = 0.f;
    if (lane < 48) {
        const float2* Wl = (const float2*)Wlw;
        float2 wsv = Wl[lane];        // weights for sum_sel (components 2l, 2l+1)
        float2 wnv = Wl[48 + lane];   // weights for sum_neigh
        tv = ssx * wsv.x + ssy * wsv.y + snx * wnv.x + sny * wnv.y;
    }
    tv = wave_sum(tv);
    if (lane == 0) wp[wid] = 1.f / (1.f + expf(-tv));
}

// ---- K_pass3: A_x (ballot-sparse over wp!=0) -> out = proj(expmap0(updated + relu(A_x)))
__global__ __launch_bounds__(256) void k_pass3(
    const float* __restrict__ up, const unsigned* __restrict__ upb,
    const int* __restrict__ srcp, const int* __restrict__ cnt,
    const float* __restrict__ wp, float* __restrict__ out, int n)
{
    int wid = (blockIdx.x * blockDim.x + threadIdx.x) >> 6;
    int lane = threadIdx.x & 63;
    if (wid >= n) return;
    int m = cnt[wid]; if (m > CAP) m = CAP;
    const int* sp = srcp + (size_t)wid * CAP;
    int jl = 0; float pl = 0.f;
    if (lane < m) { jl = sp[lane]; pl = wp[jl]; }
    unsigned long long ball = __ballot(pl != 0.f);
    float ax = 0.f, ay = 0.f;
    while (ball) {
        int b = __ffsll(ball) - 1;
        ball &= ball - 1;
        int j = __shfl(jl, b, 64);
        float p = __shfl(pl, b, 64);
        if (lane < 48) {
            unsigned u = upb[(size_t)j * 48 + lane];
            ax = fmaf(p, bf_lo(u), ax);
            ay = fmaf(p, bf_hi(u), ay);
        }
    }
    ax = fmaxf(ax, 0.f);
    ay = fmaxf(ay, 0.f);
    float2 own = (lane < 48) ? ((const float2*)(up + (size_t)wid * FDIM))[lane]
                             : make_float2(0.f, 0.f);
    float ox = own.x + ax, oy = own.y + ay;
    float ss = wave_sum(ox * ox + oy * oy);
    float norm = fmaxf(sqrtf(ss), 1e-15f);
    float th = tanhf(norm);
    float s = th / norm;
    const float maxn = 1.0f - 4e-3f;
    if (th > maxn) s = maxn / norm;
    if (lane < 48) {
        float2* o = (float2*)(out + (size_t)wid * FDIM);
        o[lane] = make_float2(s * ox, s * oy);
    }
}

extern "C" void kernel_launch(void* const* d_in, const int* in_sizes, int n_in,
                              void* d_out, int out_size, void* d_ws, size_t ws_size,
                              hipStream_t stream) {
    const float* x   = (const float*)d_in[0];
    const int*  eidx = (const int*)d_in[1];
    const float* Wup = (const float*)d_in[2];
    const float* Wlw = (const float*)d_in[3];
    float* out = (float*)d_out;

    int N = in_sizes[0] / FDIM;
    int E = in_sizes[1] / 2;
    const int* row = eidx;
    const int* col = eidx + E;

    char* ws = (char*)d_ws;
    size_t off = 0;
    auto alloc = [&](size_t bytes) {
        void* p = ws + off;
        off += (bytes + 255) & ~(size_t)255;
        return p;
    };
    float*    x_tan = (float*)alloc((size_t)N * FDIM * 4);
    float*    up    = (float*)alloc((size_t)N * FDIM * 4);
    unsigned* xtb   = (unsigned*)alloc((size_t)N * 48 * 4);
    unsigned* upb   = (unsigned*)alloc((size_t)N * 48 * 4);
    int*      deg   = (int*)alloc((size_t)N * 4);
    int*      cnt   = (int*)alloc((size_t)N * 4);
    float*    sel   = (float*)alloc((size_t)N * 4);
    float*    wp    = (float*)alloc((size_t)N * 4);
    int*      srcp  = (int*)alloc((size_t)N * CAP * 4);

    hipMemsetAsync(deg, 0, (size_t)N * 4, stream);
    hipMemsetAsync(cnt, 0, (size_t)N * 4, stream);

    dim3 blk(256);
    int Gedge = (E + 511) / 512;       // 2 edges per thread
    int Ggemm = (N + 7) / 8;
    dim3 gridF(Gedge + Ggemm);
    dim3 gridN4((N + 3) / 4);          // wave-per-node kernels

    k_fused<<<gridF, blk, 0, stream>>>(x, Wup, row, col, x_tan, xtb, up, upb,
                                       deg, cnt, srcp, N, E, Gedge);
    k_pass1<<<gridN4, blk, 0, stream>>>(x_tan, xtb, srcp, cnt, deg, sel, N);
    k_pass2<<<gridN4, blk, 0, stream>>>(upb, srcp, cnt, sel, Wlw, wp, N);
    k_pass3<<<gridN4, blk, 0, stream>>>(up, upb, srcp, cnt, wp, out, N);
}

// Round 4
// 221.886 us; speedup vs baseline: 1.8830x; 1.0321x over previous
//
#include <hip/hip_runtime.h>
#include <math.h>

#define FDIM 96
#define CAP 64

static __device__ __forceinline__ float wave_sum(float v) {
    for (int off = 32; off; off >>= 1) v += __shfl_xor(v, off, 64);
    return v;
}
static __device__ __forceinline__ float half_sum(float v) {   // within 32-aligned half-wave
    for (int off = 16; off; off >>= 1) v += __shfl_xor(v, off, 64);
    return v;
}
static __device__ __forceinline__ float bf_lo(unsigned u) { return __uint_as_float(u << 16); }
static __device__ __forceinline__ float bf_hi(unsigned u) { return __uint_as_float(u & 0xffff0000u); }
static __device__ __forceinline__ unsigned bf_rne(float f) {
    unsigned x = __float_as_uint(f);
    return (x + 0x7fffu + ((x >> 16) & 1u)) >> 16;
}

// ---- K_fused: [edge blocks: deg/cnt/srcp-T build] ++ [gemm blocks: logmap+gemm+bf16 packs]
__global__ __launch_bounds__(512) void k_fused(
    const float* __restrict__ x, const float* __restrict__ W,
    const int* __restrict__ row, const int* __restrict__ col,
    float* __restrict__ xt, unsigned* __restrict__ xtb,
    float* __restrict__ up, unsigned* __restrict__ upb,
    int* __restrict__ deg, int* __restrict__ cnt,
    unsigned short* __restrict__ srcp,
    int n, int E, int edgeBlocks)
{
    __shared__ float Ws[FDIM][49];     // one 48-wide k-chunk of W
    __shared__ float xs[16][FDIM];
    int t = threadIdx.x;

    if ((int)blockIdx.x < edgeBlocks) {           // ---- edge path: 4 edges/thread
        int base = blockIdx.x * 2048 + t * 4;
        if (base < E) {
            int4 rr = *(const int4*)(row + base);
            int4 cc = *(const int4*)(col + base);
            atomicAdd(&deg[rr.x], 1);
            atomicAdd(&deg[rr.y], 1);
            atomicAdd(&deg[rr.z], 1);
            atomicAdd(&deg[rr.w], 1);
            int p0 = atomicAdd(&cnt[cc.x], 1);
            int p1 = atomicAdd(&cnt[cc.y], 1);
            int p2 = atomicAdd(&cnt[cc.z], 1);
            int p3 = atomicAdd(&cnt[cc.w], 1);
            if (p0 < CAP) srcp[(size_t)p0 * n + cc.x] = (unsigned short)rr.x;
            if (p1 < CAP) srcp[(size_t)p1 * n + cc.y] = (unsigned short)rr.y;
            if (p2 < CAP) srcp[(size_t)p2 * n + cc.z] = (unsigned short)rr.z;
            if (p3 < CAP) srcp[(size_t)p3 * n + cc.w] = (unsigned short)rr.w;
        }
        return;
    }

    // ---- gemm path: 16 rows per 512-thread block
    int row0 = ((int)blockIdx.x - edgeBlocks) * 16;
    int r = t >> 5, c = t & 31;
    int gr = row0 + r;
    // logmap0
    float v0 = 0.f, v1 = 0.f, v2 = 0.f;
    if (gr < n) {
        const float* xr = x + (size_t)gr * FDIM;
        v0 = xr[c]; v1 = xr[c + 32]; v2 = xr[c + 64];
    }
    float ss = half_sum(v0 * v0 + v1 * v1 + v2 * v2);
    float norm = fmaxf(sqrtf(ss), 1e-15f);
    float s = atanhf(fminf(norm, 1.0f)) / norm;
    float u0 = v0 * s, u1 = v1 * s, u2 = v2 * s;
    xs[r][c] = u0; xs[r][c + 32] = u1; xs[r][c + 64] = u2;
    if (gr < n) {
        float* o = xt + (size_t)gr * FDIM;
        o[c] = u0; o[c + 32] = u1; o[c + 64] = u2;
    }
    __syncthreads();
    for (int idx = t; idx < 16 * 48; idx += 512) {     // pack bf16 x_tan
        int r2 = idx / 48, cc = idx % 48, g = row0 + r2;
        if (g < n)
            xtb[(size_t)g * 48 + cc] = bf_rne(xs[r2][2 * cc]) | (bf_rne(xs[r2][2 * cc + 1]) << 16);
    }
    // gemm: updated[c] = sum_k xt[k] * W[c][k], two 48-wide k-chunks
    float a0 = 0.f, a1 = 0.f, a2 = 0.f;
    for (int ch = 0; ch < 2; ++ch) {
        __syncthreads();
        for (int idx = t; idx < FDIM * 48; idx += 512) {
            int cw = idx / 48, kk = idx % 48;
            Ws[cw][kk] = W[(size_t)cw * FDIM + ch * 48 + kk];
        }
        __syncthreads();
        const float* xrow = &xs[r][ch * 48];
#pragma unroll 12
        for (int kk = 0; kk < 48; ++kk) {
            float xv = xrow[kk];
            a0 = fmaf(xv, Ws[c][kk], a0);
            a1 = fmaf(xv, Ws[c + 32][kk], a1);
            a2 = fmaf(xv, Ws[c + 64][kk], a2);
        }
    }
    a0 = a0 > 0.f ? a0 : 0.01f * a0;
    a1 = a1 > 0.f ? a1 : 0.01f * a1;
    a2 = a2 > 0.f ? a2 : 0.01f * a2;
    if (gr < n) {
        float* o = up + (size_t)gr * FDIM;
        o[c] = a0; o[c + 32] = a1; o[c + 64] = a2;
    }
    __syncthreads();
    xs[r][c] = a0; xs[r][c + 32] = a1; xs[r][c + 64] = a2;
    __syncthreads();
    for (int idx = t; idx < 16 * 48; idx += 512) {     // pack bf16 updated
        int r2 = idx / 48, cc = idx % 48, g = row0 + r2;
        if (g < n)
            upb[(size_t)g * 48 + cc] = bf_rne(xs[r2][2 * cc]) | (bf_rne(xs[r2][2 * cc + 1]) << 16);
    }
}

// ---- K_pass1: score via bf16 gather (8x unroll) + fp32 borderline recompute -> sel
__global__ __launch_bounds__(256) void k_pass1(
    const float* __restrict__ xt, const unsigned* __restrict__ xtb,
    const unsigned short* __restrict__ srcp, const int* __restrict__ cnt,
    const int* __restrict__ deg, float* __restrict__ sel, int n)
{
    int wid = (blockIdx.x * blockDim.x + threadIdx.x) >> 6;
    int lane = threadIdx.x & 63;
    if (wid >= n) return;
    int dsf = deg[wid];
    float di = dsf > 0 ? (float)(1.0 / sqrt((double)dsf)) : 0.f;
    int m = cnt[wid]; if (m > CAP) m = CAP;
    int jl = 0; float dvl = 0.f;
    if (lane < m) {
        jl = srcp[(size_t)lane * n + wid];
        int dj = deg[jl];
        dvl = dj > 0 ? (float)(1.0 / sqrt((double)dj)) : 0.f;
    }
    unsigned qo = (lane < 48) ? xtb[(size_t)wid * 48 + lane] : 0u;
    float accx[8], accy[8];
#pragma unroll
    for (int u = 0; u < 8; ++u) { accx[u] = 0.f; accy[u] = 0.f; }
    accx[0] = bf_lo(qo); accy[0] = bf_hi(qo);
    for (int k = 0; k < m; k += 8) {
        int j[8]; float cf[8];
#pragma unroll
        for (int u = 0; u < 8; ++u) {
            j[u]  = __shfl(jl, k + u, 64);
            cf[u] = -di * __shfl(dvl, k + u, 64);
        }
#pragma unroll
        for (int u = 0; u < 8; ++u) {
            if (k + u < m && lane < 48) {
                unsigned q = xtb[(size_t)j[u] * 48 + lane];
                accx[u] = fmaf(cf[u], bf_lo(q), accx[u]);
                accy[u] = fmaf(cf[u], bf_hi(q), accy[u]);
            }
        }
    }
    float ix = ((accx[0] + accx[1]) + (accx[2] + accx[3])) + ((accx[4] + accx[5]) + (accx[6] + accx[7]));
    float iy = ((accy[0] + accy[1]) + (accy[2] + accy[3])) + ((accy[4] + accy[5]) + (accy[6] + accy[7]));
    float sc = wave_sum(fabsf(ix) + fabsf(iy));
    if (sc > 0.95f && sc < 1.05f) {          // borderline: exact fp32 recompute
        float2 own = (lane < 48) ? ((const float2*)(xt + (size_t)wid * FDIM))[lane]
                                 : make_float2(0.f, 0.f);
        float fx[4], fy[4];
#pragma unroll
        for (int u = 0; u < 4; ++u) { fx[u] = 0.f; fy[u] = 0.f; }
        fx[0] = own.x; fy[0] = own.y;
        for (int k = 0; k < m; k += 4) {
            int jj[4]; float cf[4];
#pragma unroll
            for (int u = 0; u < 4; ++u) {
                jj[u] = __shfl(jl, k + u, 64);
                cf[u] = -di * __shfl(dvl, k + u, 64);
            }
#pragma unroll
            for (int u = 0; u < 4; ++u) {
                if (k + u < m && lane < 48) {
                    float2 v = ((const float2*)(xt + (size_t)jj[u] * FDIM))[lane];
                    fx[u] = fmaf(cf[u], v.x, fx[u]);
                    fy[u] = fmaf(cf[u], v.y, fy[u]);
                }
            }
        }
        float rx = (fx[0] + fx[1]) + (fx[2] + fx[3]);
        float ry = (fy[0] + fy[1]) + (fy[2] + fy[3]);
        sc = wave_sum(fabsf(rx) + fabsf(ry));
    }
    if (lane == 0) sel[wid] = (sc > 1.0f) ? 1.f : 0.f;
}

// ---- K_pass2: only nodes with sel!=0 need wp (sigmoid of gathered sums)
__global__ __launch_bounds__(256) void k_pass2(
    const unsigned* __restrict__ upb, const unsigned short* __restrict__ srcp,
    const int* __restrict__ cnt, const float* __restrict__ sel,
    const float* __restrict__ Wlw, float* __restrict__ wp, int n)
{
    int wid = (blockIdx.x * blockDim.x + threadIdx.x) >> 6;
    int lane = threadIdx.x & 63;
    if (wid >= n) return;
    if (sel[wid] == 0.f) { if (lane == 0) wp[wid] = 0.f; return; }
    int m = cnt[wid]; if (m > CAP) m = CAP;
    int jl = 0; float sl = 0.f;
    if (lane < m) { jl = srcp[(size_t)lane * n + wid]; sl = sel[jl]; }
    float snx = 0.f, sny = 0.f, ssx = 0.f, ssy = 0.f;
    for (int k = 0; k < m; ++k) {
        int j = __shfl(jl, k, 64);
        float sj = __shfl(sl, k, 64);
        if (lane < 48) {
            unsigned q = upb[(size_t)j * 48 + lane];
            float vx = bf_lo(q), vy = bf_hi(q);
            snx += vx; sny += vy;
            ssx = fmaf(sj, vx, ssx); ssy = fmaf(sj, vy, ssy);
        }
    }
    float tv = 0.f;
    if (lane < 48) {
        const float2* Wl = (const float2*)Wlw;
        float2 wsv = Wl[lane];        // weights for sum_sel (components 2l, 2l+1)
        float2 wnv = Wl[48 + lane];   // weights for sum_neigh
        tv = ssx * wsv.x + ssy * wsv.y + snx * wnv.x + sny * wnv.y;
    }
    tv = wave_sum(tv);
    if (lane == 0) wp[wid] = 1.f / (1.f + expf(-tv));
}

// ---- K_pass3: A_x (ballot-sparse over wp!=0) -> out = proj(expmap0(updated + relu(A_x)))
__global__ __launch_bounds__(256) void k_pass3(
    const float* __restrict__ up, const unsigned* __restrict__ upb,
    const unsigned short* __restrict__ srcp, const int* __restrict__ cnt,
    const float* __restrict__ wp, float* __restrict__ out, int n)
{
    int wid = (blockIdx.x * blockDim.x + threadIdx.x) >> 6;
    int lane = threadIdx.x & 63;
    if (wid >= n) return;
    int m = cnt[wid]; if (m > CAP) m = CAP;
    int jl = 0; float pl = 0.f;
    if (lane < m) { jl = srcp[(size_t)lane * n + wid]; pl = wp[jl]; }
    unsigned long long ball = __ballot(pl != 0.f);
    float ax = 0.f, ay = 0.f;
    while (ball) {
        int b = __ffsll(ball) - 1;
        ball &= ball - 1;
        int j = __shfl(jl, b, 64);
        float p = __shfl(pl, b, 64);
        if (lane < 48) {
            unsigned u = upb[(size_t)j * 48 + lane];
            ax = fmaf(p, bf_lo(u), ax);
            ay = fmaf(p, bf_hi(u), ay);
        }
    }
    ax = fmaxf(ax, 0.f);
    ay = fmaxf(ay, 0.f);
    float2 own = (lane < 48) ? ((const float2*)(up + (size_t)wid * FDIM))[lane]
                             : make_float2(0.f, 0.f);
    float ox = own.x + ax, oy = own.y + ay;
    float ss = wave_sum(ox * ox + oy * oy);
    float norm = fmaxf(sqrtf(ss), 1e-15f);
    float th = tanhf(norm);
    float s = th / norm;
    const float maxn = 1.0f - 4e-3f;
    if (th > maxn) s = maxn / norm;
    if (lane < 48) {
        float2* o = (float2*)(out + (size_t)wid * FDIM);
        o[lane] = make_float2(s * ox, s * oy);
    }
}

extern "C" void kernel_launch(void* const* d_in, const int* in_sizes, int n_in,
                              void* d_out, int out_size, void* d_ws, size_t ws_size,
                              hipStream_t stream) {
    const float* x   = (const float*)d_in[0];
    const int*  eidx = (const int*)d_in[1];
    const float* Wup = (const float*)d_in[2];
    const float* Wlw = (const float*)d_in[3];
    float* out = (float*)d_out;

    int N = in_sizes[0] / FDIM;
    int E = in_sizes[1] / 2;
    const int* row = eidx;
    const int* col = eidx + E;

    char* ws = (char*)d_ws;
    size_t off = 0;
    auto alloc = [&](size_t bytes) {
        void* p = ws + off;
        off += (bytes + 255) & ~(size_t)255;
        return p;
    };
    float*          x_tan = (float*)alloc((size_t)N * FDIM * 4);
    float*          up    = (float*)alloc((size_t)N * FDIM * 4);
    unsigned*       xtb   = (unsigned*)alloc((size_t)N * 48 * 4);
    unsigned*       upb   = (unsigned*)alloc((size_t)N * 48 * 4);
    int*            deg   = (int*)alloc((size_t)N * 4);
    int*            cnt   = (int*)alloc((size_t)N * 4);
    float*          sel   = (float*)alloc((size_t)N * 4);
    float*          wp    = (float*)alloc((size_t)N * 4);
    unsigned short* srcp  = (unsigned short*)alloc((size_t)CAP * N * 2);

    hipMemsetAsync(deg, 0, (size_t)N * 4, stream);
    hipMemsetAsync(cnt, 0, (size_t)N * 4, stream);

    int Gedge = (E + 2047) / 2048;     // 4 edges per thread, 512-thread blocks
    int Ggemm = (N + 15) / 16;
    dim3 gridF(Gedge + Ggemm);
    dim3 blkF(512);
    dim3 blk(256);
    dim3 gridN4((N + 3) / 4);          // wave-per-node kernels

    k_fused<<<gridF, blkF, 0, stream>>>(x, Wup, row, col, x_tan, xtb, up, upb,
                                        deg, cnt, srcp, N, E, Gedge);
    k_pass1<<<gridN4, blk, 0, stream>>>(x_tan, xtb, srcp, cnt, deg, sel, N);
    k_pass2<<<gridN4, blk, 0, stream>>>(upb, srcp, cnt, sel, Wlw, wp, N);
    k_pass3<<<gridN4, blk, 0, stream>>>(up, upb, srcp, cnt, wp, out, N);
}